// Round 9
// baseline (248.354 us; speedup 1.0000x reference)
//
#include <hip/hip_runtime.h>

// MultiHeadAttention: B=2, S=2048, D=1024, H=16, DK=64, causal. FP32 I/O.
// R18: two levers.
//  attn: q-tile PAIRING. Item = (bh, {2j,2j+1}) sharing one K/V stream: 8 ds_read of K feed
//  32 MFMAs (was 16), staging+barriers per unit work halve (512 items, 8704 tiles vs 16896),
//  and the two q-tiles' S^T->exp->pack->PV chains are independent -> 2x ILP inside the wave
//  (R8 counters: MfmaUtil 13 / VALUBusy 26 / nothing saturated = wave-serial-chain bound).
//  3-buffer counted-vmcnt kept: vmcnt(4) through kt=2j (S(last) issued by kt=2j-1 or
//  prologue), vmcnt(0) at the B-diagonal tile. LPT heaviest-pair-first, global counter.
//  qkv: XCD-contiguous remap ALONE on the untouched R0 structure (R3 proved this decode cuts
//  FETCH 101->22.6 MB; R3/R4 losses came from their bundled dbuf/BK changes, not the remap).
// out-proj (R4 + XCD remap), cvt unchanged.

typedef unsigned short u16;
typedef unsigned int u32;
typedef __attribute__((ext_vector_type(8))) __bf16 bf16x8;
typedef __attribute__((ext_vector_type(8))) unsigned short us8;
typedef __attribute__((ext_vector_type(4))) float f32x4;

#define S_LEN 2048
#define D_DIM 1024
#define NH 16
#define DKH 64
#define Mi 1048576ULL

__device__ __forceinline__ u16 f2bf(float f) {
  return __builtin_bit_cast(u16, (__bf16)f);   // RNE; HW cvt on gfx950
}
__device__ __forceinline__ bf16x8 ld_frag(const u16* p) {
  us8 v = *(const us8*)p;
  return __builtin_bit_cast(bf16x8, v);
}
__device__ __forceinline__ float fast_exp2(float x) {
  float r;
  asm("v_exp_f32 %0, %1" : "=v"(r) : "v"(x));   // scores pre-scaled: no denorm/range fixup needed
  return r;
}
// async global->LDS, 16B per lane; lds base must be wave-uniform (HW: base + lane*16)
__device__ __forceinline__ void gl2lds16(const u16* g, u16* l) {
  __builtin_amdgcn_global_load_lds(
      (__attribute__((address_space(1))) void*)(g),
      (__attribute__((address_space(3))) void*)(l), 16, 0, 0);
}

// ---- Prepass: convert q,k,v (4Mi elems each) + Wq,Wk,Wv,Wo (1Mi each) to bf16.
// Also zeroes the attn work-queue counter (d_out[0]; out-proj overwrites d_out later).
__global__ __launch_bounds__(256, 1) void cvt_all(
    const float* __restrict__ q, const float* __restrict__ k, const float* __restrict__ v,
    const float* __restrict__ wq, const float* __restrict__ wk,
    const float* __restrict__ wv, const float* __restrict__ wo,
    u16* __restrict__ dst, u32* __restrict__ cnt)
{
  if (blockIdx.x == 0 && threadIdx.x == 0) *cnt = 0;
  size_t e0 = ((size_t)blockIdx.x * 256 + threadIdx.x) * 8;
  const float* s;
  if      (e0 <  4*Mi) s = q  + e0;
  else if (e0 <  8*Mi) s = k  + (e0 - 4*Mi);
  else if (e0 < 12*Mi) s = v  + (e0 - 8*Mi);
  else if (e0 < 13*Mi) s = wq + (e0 - 12*Mi);
  else if (e0 < 14*Mi) s = wk + (e0 - 13*Mi);
  else if (e0 < 15*Mi) s = wv + (e0 - 14*Mi);
  else                 s = wo + (e0 - 15*Mi);
  float4 a = ((const float4*)s)[0];
  float4 b = ((const float4*)s)[1];
  us8 o;
  o[0]=f2bf(a.x); o[1]=f2bf(a.y); o[2]=f2bf(a.z); o[3]=f2bf(a.w);
  o[4]=f2bf(b.x); o[5]=f2bf(b.y); o[6]=f2bf(b.z); o[7]=f2bf(b.w);
  *(us8*)(dst + e0) = o;
}

// ---- QKV projection, R0 structure + XCD-contiguous remap (768 = 8 XCD * 96; verified
// FETCH 101->22.6 MB in R3). z=0 (Q): (B,H,S,DK) scaled; z=1 (K); z=2 (V): (B,H,DK,S).
__global__ __launch_bounds__(256, 1) void gemm_qkv_bb(
    const u16* __restrict__ Aq, const u16* __restrict__ Ak, const u16* __restrict__ Av,
    const u16* __restrict__ Wqb, const u16* __restrict__ Wkb, const u16* __restrict__ Wvb,
    const float* __restrict__ bq, const float* __restrict__ bk, const float* __restrict__ bv,
    u16* __restrict__ Oq, u16* __restrict__ Ok, u16* __restrict__ Ov, float qscale)
{
  const int bid = blockIdx.x;
  const int o   = (bid & 7) * 96 + (bid >> 3);
  const int z   = o >> 8;                 // 0..2
  const int rem = o & 255;
  const int mblk = (rem >> 3) * 128;      // M = 4096 -> 32
  const int nblk = (rem & 7) * 128;       // N = 1024 -> 8

  const u16* A = (z == 0) ? Aq : (z == 1) ? Ak : Av;
  const u16* W = (z == 0) ? Wqb : (z == 1) ? Wkb : Wvb;
  const float* bias = (z == 0) ? bq : (z == 1) ? bk : bv;
  u16* out = (z == 0) ? Oq : (z == 1) ? Ok : Ov;
  const float scale = (z == 0) ? qscale : 1.0f;
  const int K = 1024;

  __shared__ u16 lA[128 * 32];
  __shared__ u16 lB[128 * 32];
  const int t = threadIdx.x;
  const int w = t >> 6, l = t & 63;
  const int wm = (w & 1) * 64, wn = (w >> 1) * 64;
  const int lr = l & 15, lq = l >> 4;
  const int srow = l >> 2, scol = (l & 3) * 8;

  f32x4 acc[4][4] = {};

  for (int k0 = 0; k0 < K; k0 += 32) {
    __syncthreads();
    #pragma unroll
    for (int r = 0; r < 2; ++r) {
      int grp = r * 4 + w;
      gl2lds16(A + (size_t)(mblk + grp * 16 + srow) * K + k0 + scol, &lA[grp * 512]);
      gl2lds16(W + (size_t)(nblk + grp * 16 + srow) * K + k0 + scol, &lB[grp * 512]);
    }
    __syncthreads();
    bf16x8 aF[4], bF[4];
    #pragma unroll
    for (int mt = 0; mt < 4; ++mt)
      aF[mt] = ld_frag(&lA[(wm + mt * 16 + lr) * 32 + lq * 8]);
    #pragma unroll
    for (int nt = 0; nt < 4; ++nt)
      bF[nt] = ld_frag(&lB[(wn + nt * 16 + lr) * 32 + lq * 8]);
    #pragma unroll
    for (int mt = 0; mt < 4; ++mt)
      #pragma unroll
      for (int nt = 0; nt < 4; ++nt)
        acc[mt][nt] = __builtin_amdgcn_mfma_f32_16x16x32_bf16(aF[mt], bF[nt], acc[mt][nt], 0, 0, 0);
  }

  #pragma unroll
  for (int mt = 0; mt < 4; ++mt)
    #pragma unroll
    for (int nt = 0; nt < 4; ++nt)
      #pragma unroll
      for (int r = 0; r < 4; ++r) {
        int rowg = mblk + wm + mt * 16 + lq * 4 + r;   // C/D: row=(lane>>4)*4+reg
        int colg = nblk + wn + nt * 16 + lr;           //      col=lane&15
        float v = (acc[mt][nt][r] + bias[colg]) * scale;
        int b = rowg >> 11, s = rowg & 2047;
        int h = colg >> 6, dk = colg & 63;
        if (z != 2)
          out[(((size_t)(b * NH + h)) * S_LEN + s) * DKH + dk] = f2bf(v);
        else
          out[(((size_t)(b * NH + h)) * DKH + dk) * S_LEN + s] = f2bf(v);
      }
}

// ---- Out-proj, bf16 -> fp32. 128x64 tile, BK=64, single-buffer 2-sync (R4 version),
// flattened 512-grid with XCD-contiguous remap.
__global__ __launch_bounds__(256, 1) void gemm_out_bb(
    const u16* __restrict__ A, const u16* __restrict__ W,
    const float* __restrict__ bias, float* __restrict__ out)
{
  const int K = 1024;
  __shared__ u16 lA[128 * 64];   // 16 KiB
  __shared__ u16 lB[64 * 64];    //  8 KiB
  const int bid = blockIdx.x;
  const int o   = (bid & 7) * 64 + (bid >> 3);   // bijective: 512 = 8 XCD * 64
  const int mblk = (o >> 4) * 128, nblk = (o & 15) * 64;
  const int t = threadIdx.x;
  const int w = t >> 6, l = t & 63;
  const int wm = (w & 1) * 64, wn = (w >> 1) * 32;
  const int lr = l & 15, lq = l >> 4;
  const int srow = l >> 3;
  const int sgr  = (l & 7) ^ srow;

  f32x4 acc[4][2] = {};

  for (int k0 = 0; k0 < K; k0 += 64) {
    __syncthreads();
    #pragma unroll
    for (int i = 0; i < 4; ++i) {
      int chunk = w * 4 + i;
      int row = chunk * 8 + srow;
      gl2lds16(A + (size_t)(mblk + row) * K + k0 + sgr * 8, &lA[chunk * 512]);
    }
    #pragma unroll
    for (int i = 0; i < 2; ++i) {
      int chunk = w * 2 + i;               // 8 chunks of 8 rows for B
      int row = chunk * 8 + srow;
      gl2lds16(W + (size_t)(nblk + row) * K + k0 + sgr * 8, &lB[chunk * 512]);
    }
    __syncthreads();
    #pragma unroll
    for (int kk = 0; kk < 2; ++kk) {
      bf16x8 aF[4], bF[2];
      #pragma unroll
      for (int mt = 0; mt < 4; ++mt)
        aF[mt] = ld_frag(&lA[(wm + mt * 16 + lr) * 64 + ((kk * 4 + lq) ^ (lr & 7)) * 8]);
      #pragma unroll
      for (int nt = 0; nt < 2; ++nt)
        bF[nt] = ld_frag(&lB[(wn + nt * 16 + lr) * 64 + ((kk * 4 + lq) ^ (lr & 7)) * 8]);
      #pragma unroll
      for (int mt = 0; mt < 4; ++mt)
        #pragma unroll
        for (int nt = 0; nt < 2; ++nt)
          acc[mt][nt] = __builtin_amdgcn_mfma_f32_16x16x32_bf16(aF[mt], bF[nt], acc[mt][nt], 0, 0, 0);
    }
  }

  #pragma unroll
  for (int mt = 0; mt < 4; ++mt)
    #pragma unroll
    for (int nt = 0; nt < 2; ++nt)
      #pragma unroll
      for (int r = 0; r < 4; ++r) {
        int rowg = mblk + wm + mt * 16 + lq * 4 + r;
        int colg = nblk + wn + nt * 16 + lr;
        out[(size_t)rowg * D_DIM + colg] = acc[mt][nt][r] + bias[colg];
      }
}

// ---- MFMA flash attention (S^T, no-max softmax, register-resident P), causal.
// R18: q-tile pairing. Item = (bh, qta=2j, qtb=2j+1); one K/V stream serves both q-tiles
// (each kb/vb ds_read feeds 2 MFMAs; 2 independent softmax chains = 2x wave ILP).
// 512 items, LPT heaviest-pair-first, global counter. 3-buffer counted vmcnt:
// outstanding at tile-kt entry = S(kt)+S(kt+1)=8 -> vmcnt(4); B-diag tile -> vmcnt(0).
// Tile roles: kt<qta both clean; kt==qta A-diag+B-clean; kt==qtb B-diag only.
// S^T MFMA nt consumes K rows sigma(nt,m)=32(nt>>1)+8(m>>2)+4(nt&1)+(m&3): its C regs
// give lane lq the k-indices 8lq+j (j=4(nt&1)+r) == the PV A-operand packing. Zero P movement.
// LDS swizzle swz(row)=(row&3)|(((row>>3)&1)<<2): K-reads hit slot=(4ks+lq)^(lr&7) (verified even).
__global__ __launch_bounds__(256, 1) void attn_fused(
    const u16* __restrict__ Q, const u16* __restrict__ K,
    const u16* __restrict__ Vt, u16* __restrict__ O, u32* __restrict__ cnt)
{
  __shared__ u16 lK[3][64 * 64];   // 24 KiB
  __shared__ u16 lV[3][64 * 64];   // 24 KiB
  __shared__ int s_item;

  const int t = threadIdx.x;
  const int w = t >> 6, l = t & 63;
  const int lr = l & 15, lq = l >> 4;
  const int srow8 = l >> 3;            // staging: row within 8-row group
  const int schunk = l & 7;            // staging: LDS slot chunk this lane fills

  #define STAGE(T, bsel)                                                          \
    do {                                                                          \
      _Pragma("unroll")                                                           \
      for (int r2 = 0; r2 < 2; ++r2) {                                            \
        int grp = r2 * 4 + w;                                                     \
        int row = grp * 8 + srow8;                                                \
        int sw = (row & 3) | (((row >> 3) & 1) << 2);                             \
        int c = schunk ^ sw;                                                      \
        gl2lds16(Kp + (size_t)((T) * 64 + row) * DKH + c * 8, &lK[bsel][grp * 512]); \
        gl2lds16(Vp + (size_t)row * S_LEN + (T) * 64 + c * 8, &lV[bsel][grp * 512]); \
      }                                                                           \
    } while (0)

  // S^T for both q-tiles from one K read
  #define QKT_PAIR(cur, stA, stB)                                                 \
    do {                                                                          \
      _Pragma("unroll")                                                           \
      for (int ksd = 0; ksd < 2; ++ksd)                                           \
        _Pragma("unroll")                                                         \
        for (int nt = 0; nt < 4; ++nt) {                                          \
          int sig = 32 * (nt >> 1) + 8 * (lr >> 2) + 4 * (nt & 1) + (lr & 3);     \
          int slot = (ksd * 4 + lq) ^ (lr & 7);                                   \
          bf16x8 kb = ld_frag(&lK[cur][sig * 64 + slot * 8]);                     \
          stA[nt] = __builtin_amdgcn_mfma_f32_16x16x32_bf16(kb, qfA[ksd], stA[nt], 0, 0, 0); \
          stB[nt] = __builtin_amdgcn_mfma_f32_16x16x32_bf16(kb, qfB[ksd], stB[nt], 0, 0, 0); \
        }                                                                         \
    } while (0)

  // PV for both q-tiles from one V read
  #define PV_PAIR(cur, avA, avB)                                                  \
    do {                                                                          \
      _Pragma("unroll")                                                           \
      for (int ks = 0; ks < 2; ++ks) {                                            \
        bf16x8 paA = __builtin_bit_cast(bf16x8, avA[ks]);                         \
        bf16x8 paB = __builtin_bit_cast(bf16x8, avB[ks]);                         \
        _Pragma("unroll")                                                         \
        for (int dblk = 0; dblk < 4; ++dblk) {                                    \
          int d = dblk * 16 + lr;                                                 \
          int sw = (d & 3) | (((d >> 3) & 1) << 2);                               \
          int slot = (4 * ks + lq) ^ sw;                                          \
          bf16x8 vb = ld_frag(&lV[cur][d * 64 + slot * 8]);                       \
          o4A[dblk] = __builtin_amdgcn_mfma_f32_16x16x32_bf16(paA, vb, o4A[dblk], 0, 0, 0); \
          o4B[dblk] = __builtin_amdgcn_mfma_f32_16x16x32_bf16(paB, vb, o4B[dblk], 0, 0, 0); \
        }                                                                         \
      }                                                                           \
    } while (0)

  while (true) {
    __syncthreads();                   // drain prior item's LDS reads + s_item reuse (WAR)
    if (t == 0) s_item = (int)atomicAdd(cnt, 1u);
    __syncthreads();
    const int item = s_item;
    if (item >= 512) break;
    const int j  = 15 - (item >> 5);   // heaviest pair first (LPT)
    const int bh = item & 31;
    const int qta = 2 * j, qtb = 2 * j + 1;
    const int b = bh >> 4, h = bh & 15;

    const u16* Qp = Q + (size_t)bh * S_LEN * DKH;
    const u16* Kp = K + (size_t)bh * S_LEN * DKH;
    const u16* Vp = Vt + (size_t)bh * DKH * S_LEN;

    // Q fragments for both q-tiles (B-operand: n=lane&15=q, k=lq*8+j)
    const int qrowA = qta * 64 + w * 16 + lr;
    const int qrowB = qtb * 64 + w * 16 + lr;
    bf16x8 qfA[2], qfB[2];
    qfA[0] = ld_frag(Qp + (size_t)qrowA * DKH + lq * 8);
    qfA[1] = ld_frag(Qp + (size_t)qrowA * DKH + 32 + lq * 8);
    qfB[0] = ld_frag(Qp + (size_t)qrowB * DKH + lq * 8);
    qfB[1] = ld_frag(Qp + (size_t)qrowB * DKH + 32 + lq * 8);

    f32x4 o4A[4] = {}, o4B[4] = {};
    f32x4 liA = {}, liB = {};

    STAGE(0, 0);                       // prologue: tiles 0 and 1 (qtb >= 1 always)
    STAGE(1, 1);

    // ---- kt < qta: both q-tiles clean
    for (int kt = 0; kt < qta; ++kt) {
      const int cur = kt % 3;
      asm volatile("s_waitcnt vmcnt(4)\n\ts_barrier" ::: "memory");
      if (kt + 2 <= qtb) STAGE(kt + 2, (kt + 2) % 3);

      f32x4 stA[4] = {}, stB[4] = {};
      QKT_PAIR(cur, stA, stB);

      us8 avA[2], avB[2];
      #pragma unroll
      for (int ks = 0; ks < 2; ++ks)
        #pragma unroll
        for (int rr = 0; rr < 4; ++rr) {
          float eA0 = fast_exp2(stA[2 * ks][rr]);
          float eA1 = fast_exp2(stA[2 * ks + 1][rr]);
          float eB0 = fast_exp2(stB[2 * ks][rr]);
          float eB1 = fast_exp2(stB[2 * ks + 1][rr]);
          liA[rr] += eA0 + eA1;
          liB[rr] += eB0 + eB1;
          avA[ks][rr] = f2bf(eA0); avA[ks][4 + rr] = f2bf(eA1);
          avB[ks][rr] = f2bf(eB0); avB[ks][4 + rr] = f2bf(eB1);
        }
      PV_PAIR(cur, avA, avB);
    }

    // ---- kt == qta: A diagonal (mask), B clean
    {
      const int cur = qta % 3;
      asm volatile("s_waitcnt vmcnt(4)\n\ts_barrier" ::: "memory");

      f32x4 stA[4] = {}, stB[4] = {};
      QKT_PAIR(cur, stA, stB);

      const int qloc = w * 16 + lr;
      us8 avA[2], avB[2];
      #pragma unroll
      for (int ks = 0; ks < 2; ++ks)
        #pragma unroll
        for (int rr = 0; rr < 4; ++rr) {
          int kk0 = 32 * ks + 8 * lq + rr;        // nt = 2ks   -> 4*(nt&1)=0
          int kk1 = 32 * ks + 8 * lq + 4 + rr;    // nt = 2ks+1 -> 4*(nt&1)=4
          float eA0 = (kk0 > qloc) ? 0.0f : fast_exp2(stA[2 * ks][rr]);
          float eA1 = (kk1 > qloc) ? 0.0f : fast_exp2(stA[2 * ks + 1][rr]);
          float eB0 = fast_exp2(stB[2 * ks][rr]);
          float eB1 = fast_exp2(stB[2 * ks + 1][rr]);
          liA[rr] += eA0 + eA1;
          liB[rr] += eB0 + eB1;
          avA[ks][rr] = f2bf(eA0); avA[ks][4 + rr] = f2bf(eA1);
          avB[ks][rr] = f2bf(eB0); avB[ks][4 + rr] = f2bf(eB1);
        }
      PV_PAIR(cur, avA, avB);
    }

    // ---- kt == qtb: B diagonal only; all loads drained
    {
      const int cur = qtb % 3;
      asm volatile("s_waitcnt vmcnt(0)\n\ts_barrier" ::: "memory");

      f32x4 stB[4] = {};
      #pragma unroll
      for (int ksd = 0; ksd < 2; ++ksd)
        #pragma unroll
        for (int nt = 0; nt < 4; ++nt) {
          int sig = 32 * (nt >> 1) + 8 * (lr >> 2) + 4 * (nt & 1) + (lr & 3);
          int slot = (ksd * 4 + lq) ^ (lr & 7);
          bf16x8 kb = ld_frag(&lK[cur][sig * 64 + slot * 8]);
          stB[nt] = __builtin_amdgcn_mfma_f32_16x16x32_bf16(kb, qfB[ksd], stB[nt], 0, 0, 0);
        }

      const int qloc = w * 16 + lr;
      us8 avB[2];
      #pragma unroll
      for (int ks = 0; ks < 2; ++ks)
        #pragma unroll
        for (int rr = 0; rr < 4; ++rr) {
          int kk0 = 32 * ks + 8 * lq + rr;
          int kk1 = 32 * ks + 8 * lq + 4 + rr;
          float eB0 = (kk0 > qloc) ? 0.0f : fast_exp2(stB[2 * ks][rr]);
          float eB1 = (kk1 > qloc) ? 0.0f : fast_exp2(stB[2 * ks + 1][rr]);
          liB[rr] += eB0 + eB1;
          avB[ks][rr] = f2bf(eB0); avB[ks][4 + rr] = f2bf(eB1);
        }
      #pragma unroll
      for (int ks = 0; ks < 2; ++ks) {
        bf16x8 paB = __builtin_bit_cast(bf16x8, avB[ks]);
        #pragma unroll
        for (int dblk = 0; dblk < 4; ++dblk) {
          int d = dblk * 16 + lr;
          int sw = (d & 3) | (((d >> 3) & 1) << 2);
          int slot = (4 * ks + lq) ^ sw;
          bf16x8 vb = ld_frag(&lV[cur][d * 64 + slot * 8]);
          o4B[dblk] = __builtin_amdgcn_mfma_f32_16x16x32_bf16(paB, vb, o4B[dblk], 0, 0, 0);
        }
      }
    }

    // li finalize + epilogue for both q-tiles
    float lA_ = liA[0] + liA[1] + liA[2] + liA[3];
    lA_ += __shfl_xor(lA_, 16);
    lA_ += __shfl_xor(lA_, 32);
    float lB_ = liB[0] + liB[1] + liB[2] + liB[3];
    lB_ += __shfl_xor(lB_, 16);
    lB_ += __shfl_xor(lB_, 32);
    float riA[4], riB[4];
    #pragma unroll
    for (int r = 0; r < 4; ++r) {
      riA[r] = 1.0f / __shfl(lA_, lq * 4 + r);
      riB[r] = 1.0f / __shfl(lB_, lq * 4 + r);
    }

    const size_t obaseA = ((size_t)b * S_LEN + qta * 64 + w * 16) * D_DIM + h * DKH;
    const size_t obaseB = ((size_t)b * S_LEN + qtb * 64 + w * 16) * D_DIM + h * DKH;
    #pragma unroll
    for (int dblk = 0; dblk < 4; ++dblk)
      #pragma unroll
      for (int r = 0; r < 4; ++r) {
        O[obaseA + (size_t)(lq * 4 + r) * D_DIM + dblk * 16 + lr] = f2bf(o4A[dblk][r] * riA[r]);
        O[obaseB + (size_t)(lq * 4 + r) * D_DIM + dblk * 16 + lr] = f2bf(o4B[dblk][r] * riB[r]);
      }
  }
  #undef STAGE
  #undef QKT_PAIR
  #undef PV_PAIR
}

extern "C" void kernel_launch(void* const* d_in, const int* in_sizes, int n_in,
                              void* d_out, int out_size, void* d_ws, size_t ws_size,
                              hipStream_t stream) {
  const float* query = (const float*)d_in[0];
  const float* key   = (const float*)d_in[1];
  const float* value = (const float*)d_in[2];
  // d_in[3] = causal mask (bool, triu k=1): structure known, not read
  const float* Wq = (const float*)d_in[4];
  const float* bq = (const float*)d_in[5];
  const float* Wk = (const float*)d_in[6];
  const float* bk = (const float*)d_in[7];
  const float* Wv = (const float*)d_in[8];
  const float* bv = (const float*)d_in[9];
  const float* Wo = (const float*)d_in[10];
  const float* bo = (const float*)d_in[11];
  float* out = (float*)d_out;

  const float qscale = 0.125f * 1.44269504088896341f;  // 1/sqrt(64) * log2(e)
  dim3 blk(256);

  u16* base = (u16*)d_ws;
  u16* Qb = base;                 // (B,H,S,DK) bf16, pre-scaled   [0, 4Mi)
  u16* Kb = base + 4 * Mi;        // (B,H,S,DK) bf16               [4Mi, 8Mi)
  u16* Vb = base + 8 * Mi;        // (B,H,DK,S) bf16               [8Mi, 12Mi)

  // convert-once region [12Mi, 28Mi) elems
  u16* cvt = base + 12 * Mi;
  u16* qbf = cvt;
  u16* kbf = cvt + 4 * Mi;
  u16* vbf = cvt + 8 * Mi;
  u16* wqb = cvt + 12 * Mi;
  u16* wkb = cvt + 13 * Mi;
  u16* wvb = cvt + 14 * Mi;
  u16* wob = cvt + 15 * Mi;
  u16* Ab  = qbf;                 // aliases qbf (dead after QKV GEMM)

  // attn work counter: d_out[0] (zeroed by cvt_all, consumed by attn,
  // overwritten by gemm_out_bb afterwards; all stream-ordered).
  u32* cnt = (u32*)d_out;

  cvt_all<<<dim3(8192), blk, 0, stream>>>(query, key, value, Wq, Wk, Wv, Wo, cvt, cnt);
  gemm_qkv_bb<<<dim3(768), blk, 0, stream>>>(qbf, kbf, vbf, wqb, wkb, wvb,
                                             bq, bk, bv, Qb, Kb, Vb, qscale);
  attn_fused<<<dim3(768), blk, 0, stream>>>(Qb, Kb, Vb, Ab, cnt);
  gemm_out_bb<<<dim3(512), blk, 0, stream>>>(Ab, wob, bo, out);
}

// Round 10
// 246.162 us; speedup vs baseline: 1.0089x; 1.0089x over previous
//
#include <hip/hip_runtime.h>

// MultiHeadAttention: B=2, S=2048, D=1024, H=16, DK=64, causal. FP32 I/O.
// R19: revert R18's two losers (pairing: 512 items < 768 blocks -> no LPT balancing,
// makespan = heaviest pair; qkv remap: +3.6us by ledger accounting). Back to R17 config
// (best 230.6) + ONE change: cross-item pipelining in attn's persistent loop.
//   - next item grabbed one phase early (atomic issued at item start, result published via
//     ping-pong s_item[2] at the diag barrier -> no WAR race, grab latency hidden);
//   - during diag compute, issue next item's Q loads + STAGE(S0->buf (base+qt+1)%3,
//     S1->buf (base+qt+2)%3): those buffers' last readers (tiles qt-2, qt-1) finished at
//     the diag barrier;
//   - per-wave vmcnt order [qfN, S0n, S1n, stores]: next item's first vmcnt(4) retires
//     exactly through S0n -> counted accounting stays closed across item boundaries.
// Removes the ~1.5-2.5k cy serial {grab + Q-load + S0 cold wait} per item (~4 items/CU).
// qkv = R0 byte-exact; out-proj (R4 + XCD remap), cvt unchanged.

typedef unsigned short u16;
typedef unsigned int u32;
typedef __attribute__((ext_vector_type(8))) __bf16 bf16x8;
typedef __attribute__((ext_vector_type(8))) unsigned short us8;
typedef __attribute__((ext_vector_type(4))) float f32x4;

#define S_LEN 2048
#define D_DIM 1024
#define NH 16
#define DKH 64
#define Mi 1048576ULL

__device__ __forceinline__ u16 f2bf(float f) {
  return __builtin_bit_cast(u16, (__bf16)f);   // RNE; HW cvt on gfx950
}
__device__ __forceinline__ bf16x8 ld_frag(const u16* p) {
  us8 v = *(const us8*)p;
  return __builtin_bit_cast(bf16x8, v);
}
__device__ __forceinline__ float fast_exp2(float x) {
  float r;
  asm("v_exp_f32 %0, %1" : "=v"(r) : "v"(x));   // scores pre-scaled: no denorm/range fixup needed
  return r;
}
// async global->LDS, 16B per lane; lds base must be wave-uniform (HW: base + lane*16)
__device__ __forceinline__ void gl2lds16(const u16* g, u16* l) {
  __builtin_amdgcn_global_load_lds(
      (__attribute__((address_space(1))) void*)(g),
      (__attribute__((address_space(3))) void*)(l), 16, 0, 0);
}

// ---- Prepass: convert q,k,v (4Mi elems each) + Wq,Wk,Wv,Wo (1Mi each) to bf16.
// Also zeroes the attn work-queue counter (d_out[0]; out-proj overwrites d_out later).
__global__ __launch_bounds__(256, 1) void cvt_all(
    const float* __restrict__ q, const float* __restrict__ k, const float* __restrict__ v,
    const float* __restrict__ wq, const float* __restrict__ wk,
    const float* __restrict__ wv, const float* __restrict__ wo,
    u16* __restrict__ dst, u32* __restrict__ cnt)
{
  if (blockIdx.x == 0 && threadIdx.x == 0) *cnt = 0;
  size_t e0 = ((size_t)blockIdx.x * 256 + threadIdx.x) * 8;
  const float* s;
  if      (e0 <  4*Mi) s = q  + e0;
  else if (e0 <  8*Mi) s = k  + (e0 - 4*Mi);
  else if (e0 < 12*Mi) s = v  + (e0 - 8*Mi);
  else if (e0 < 13*Mi) s = wq + (e0 - 12*Mi);
  else if (e0 < 14*Mi) s = wk + (e0 - 13*Mi);
  else if (e0 < 15*Mi) s = wv + (e0 - 14*Mi);
  else                 s = wo + (e0 - 15*Mi);
  float4 a = ((const float4*)s)[0];
  float4 b = ((const float4*)s)[1];
  us8 o;
  o[0]=f2bf(a.x); o[1]=f2bf(a.y); o[2]=f2bf(a.z); o[3]=f2bf(a.w);
  o[4]=f2bf(b.x); o[5]=f2bf(b.y); o[6]=f2bf(b.z); o[7]=f2bf(b.w);
  *(us8*)(dst + e0) = o;
}

// ---- QKV projection, pure bf16 (R0 version, byte-exact). z=0 (Q): (B,H,S,DK) scaled;
// z=1 (K): (B,H,S,DK); z=2 (V): (B,H,DK,S).
__global__ __launch_bounds__(256, 1) void gemm_qkv_bb(
    const u16* __restrict__ Aq, const u16* __restrict__ Ak, const u16* __restrict__ Av,
    const u16* __restrict__ Wqb, const u16* __restrict__ Wkb, const u16* __restrict__ Wvb,
    const float* __restrict__ bq, const float* __restrict__ bk, const float* __restrict__ bv,
    u16* __restrict__ Oq, u16* __restrict__ Ok, u16* __restrict__ Ov, float qscale)
{
  const int z = blockIdx.z;
  const u16* A = (z == 0) ? Aq : (z == 1) ? Ak : Av;
  const u16* W = (z == 0) ? Wqb : (z == 1) ? Wkb : Wvb;
  const float* bias = (z == 0) ? bq : (z == 1) ? bk : bv;
  u16* out = (z == 0) ? Oq : (z == 1) ? Ok : Ov;
  const float scale = (z == 0) ? qscale : 1.0f;
  const int K = 1024;

  __shared__ u16 lA[128 * 32];
  __shared__ u16 lB[128 * 32];
  const int t = threadIdx.x;
  const int w = t >> 6, l = t & 63;
  const int mblk = blockIdx.y * 128, nblk = blockIdx.x * 128;
  const int wm = (w & 1) * 64, wn = (w >> 1) * 64;
  const int lr = l & 15, lq = l >> 4;
  const int srow = l >> 2, scol = (l & 3) * 8;

  f32x4 acc[4][4] = {};

  for (int k0 = 0; k0 < K; k0 += 32) {
    __syncthreads();
    #pragma unroll
    for (int r = 0; r < 2; ++r) {
      int grp = r * 4 + w;
      gl2lds16(A + (size_t)(mblk + grp * 16 + srow) * K + k0 + scol, &lA[grp * 512]);
      gl2lds16(W + (size_t)(nblk + grp * 16 + srow) * K + k0 + scol, &lB[grp * 512]);
    }
    __syncthreads();
    bf16x8 aF[4], bF[4];
    #pragma unroll
    for (int mt = 0; mt < 4; ++mt)
      aF[mt] = ld_frag(&lA[(wm + mt * 16 + lr) * 32 + lq * 8]);
    #pragma unroll
    for (int nt = 0; nt < 4; ++nt)
      bF[nt] = ld_frag(&lB[(wn + nt * 16 + lr) * 32 + lq * 8]);
    #pragma unroll
    for (int mt = 0; mt < 4; ++mt)
      #pragma unroll
      for (int nt = 0; nt < 4; ++nt)
        acc[mt][nt] = __builtin_amdgcn_mfma_f32_16x16x32_bf16(aF[mt], bF[nt], acc[mt][nt], 0, 0, 0);
  }

  #pragma unroll
  for (int mt = 0; mt < 4; ++mt)
    #pragma unroll
    for (int nt = 0; nt < 4; ++nt)
      #pragma unroll
      for (int r = 0; r < 4; ++r) {
        int rowg = mblk + wm + mt * 16 + lq * 4 + r;   // C/D: row=(lane>>4)*4+reg
        int colg = nblk + wn + nt * 16 + lr;           //      col=lane&15
        float v = (acc[mt][nt][r] + bias[colg]) * scale;
        int b = rowg >> 11, s = rowg & 2047;
        int h = colg >> 6, dk = colg & 63;
        if (z != 2)
          out[(((size_t)(b * NH + h)) * S_LEN + s) * DKH + dk] = f2bf(v);
        else
          out[(((size_t)(b * NH + h)) * DKH + dk) * S_LEN + s] = f2bf(v);
      }
}

// ---- Out-proj, bf16 -> fp32. 128x64 tile, BK=64, single-buffer 2-sync (R4 version),
// flattened 512-grid with XCD-contiguous remap.
__global__ __launch_bounds__(256, 1) void gemm_out_bb(
    const u16* __restrict__ A, const u16* __restrict__ W,
    const float* __restrict__ bias, float* __restrict__ out)
{
  const int K = 1024;
  __shared__ u16 lA[128 * 64];   // 16 KiB
  __shared__ u16 lB[64 * 64];    //  8 KiB
  const int bid = blockIdx.x;
  const int o   = (bid & 7) * 64 + (bid >> 3);   // bijective: 512 = 8 XCD * 64
  const int mblk = (o >> 4) * 128, nblk = (o & 15) * 64;
  const int t = threadIdx.x;
  const int w = t >> 6, l = t & 63;
  const int wm = (w & 1) * 64, wn = (w >> 1) * 32;
  const int lr = l & 15, lq = l >> 4;
  const int srow = l >> 3;
  const int sgr  = (l & 7) ^ srow;

  f32x4 acc[4][2] = {};

  for (int k0 = 0; k0 < K; k0 += 64) {
    __syncthreads();
    #pragma unroll
    for (int i = 0; i < 4; ++i) {
      int chunk = w * 4 + i;
      int row = chunk * 8 + srow;
      gl2lds16(A + (size_t)(mblk + row) * K + k0 + sgr * 8, &lA[chunk * 512]);
    }
    #pragma unroll
    for (int i = 0; i < 2; ++i) {
      int chunk = w * 2 + i;               // 8 chunks of 8 rows for B
      int row = chunk * 8 + srow;
      gl2lds16(W + (size_t)(nblk + row) * K + k0 + sgr * 8, &lB[chunk * 512]);
    }
    __syncthreads();
    #pragma unroll
    for (int kk = 0; kk < 2; ++kk) {
      bf16x8 aF[4], bF[2];
      #pragma unroll
      for (int mt = 0; mt < 4; ++mt)
        aF[mt] = ld_frag(&lA[(wm + mt * 16 + lr) * 64 + ((kk * 4 + lq) ^ (lr & 7)) * 8]);
      #pragma unroll
      for (int nt = 0; nt < 2; ++nt)
        bF[nt] = ld_frag(&lB[(wn + nt * 16 + lr) * 64 + ((kk * 4 + lq) ^ (lr & 7)) * 8]);
      #pragma unroll
      for (int mt = 0; mt < 4; ++mt)
        #pragma unroll
        for (int nt = 0; nt < 2; ++nt)
          acc[mt][nt] = __builtin_amdgcn_mfma_f32_16x16x32_bf16(aF[mt], bF[nt], acc[mt][nt], 0, 0, 0);
    }
  }

  #pragma unroll
  for (int mt = 0; mt < 4; ++mt)
    #pragma unroll
    for (int nt = 0; nt < 2; ++nt)
      #pragma unroll
      for (int r = 0; r < 4; ++r) {
        int rowg = mblk + wm + mt * 16 + lq * 4 + r;
        int colg = nblk + wn + nt * 16 + lr;
        out[(size_t)rowg * D_DIM + colg] = acc[mt][nt][r] + bias[colg];
      }
}

// ---- MFMA flash attention (S^T, no-max softmax, register-resident P), causal.
// R19: R17 pipeline (3-buffer counted vmcnt, LPT, diag peel, raw exp2) + cross-item
// pipelining: grab published at diag barrier (ping-pong s_item[2]); next item's Q loads
// + STAGE(S0,S1) issued during diag compute into the two free mod-3 buffers.
// vmcnt order per wave at item boundary: [qfN(2), S0n(4), S1n(4), stores(16)] ->
// next kt=0's vmcnt(4) retires through S0n; steady-state within item unchanged.
// S^T MFMA nt consumes K rows sigma(nt,m)=32(nt>>1)+8(m>>2)+4(nt&1)+(m&3): its C regs
// give lane lq the k-indices 8lq+j (j=4(nt&1)+r) == the PV A-operand packing. Zero P movement.
// LDS swizzle swz(row)=(row&3)|(((row>>3)&1)<<2): K-reads hit slot=(4ks+lq)^(lr&7) (verified even).
__global__ __launch_bounds__(256, 1) void attn_fused(
    const u16* __restrict__ Q, const u16* __restrict__ K,
    const u16* __restrict__ Vt, u16* __restrict__ O, u32* __restrict__ cnt)
{
  __shared__ u16 lK[3][64 * 64];   // 24 KiB
  __shared__ u16 lV[3][64 * 64];   // 24 KiB
  __shared__ int s_item[2];

  const int t = threadIdx.x;
  const int w = t >> 6, l = t & 63;
  const int lr = l & 15, lq = l >> 4;
  const int srow8 = l >> 3;            // staging: row within 8-row group
  const int schunk = l & 7;            // staging: LDS slot chunk this lane fills

  #define STAGE(KP, VP, T, bsel)                                                   \
    do {                                                                           \
      _Pragma("unroll")                                                            \
      for (int r2 = 0; r2 < 2; ++r2) {                                             \
        int grp = r2 * 4 + w;                                                      \
        int row = grp * 8 + srow8;                                                 \
        int sw = (row & 3) | (((row >> 3) & 1) << 2);                              \
        int c = schunk ^ sw;                                                       \
        gl2lds16((KP) + (size_t)((T) * 64 + row) * DKH + c * 8, &lK[bsel][grp * 512]); \
        gl2lds16((VP) + (size_t)row * S_LEN + (T) * 64 + c * 8, &lV[bsel][grp * 512]); \
      }                                                                            \
    } while (0)

  // ---- bootstrap: first item
  if (t == 0) s_item[0] = (int)atomicAdd(cnt, 1u);
  __syncthreads();
  int item = s_item[0];
  if (item >= 1024) return;
  int phase = 0;
  int qt = 31 - (item >> 5);           // heaviest first (LPT)
  int bh = item & 31;
  int b = bh >> 4, h = bh & 15;

  const u16* Kp = K + (size_t)bh * S_LEN * DKH;
  const u16* Vp = Vt + (size_t)bh * DKH * S_LEN;
  {
    const u16* Qp = Q + (size_t)bh * S_LEN * DKH;
    // issued before STAGE so vmcnt order is [qf, S0, S1]
    int qrow = qt * 64 + w * 16 + lr;
    // qf loads below
    (void)qrow;
  }
  bf16x8 qf0, qf1;
  {
    const u16* Qp = Q + (size_t)bh * S_LEN * DKH;
    int qrow = qt * 64 + w * 16 + lr;
    qf0 = ld_frag(Qp + (size_t)qrow * DKH + lq * 8);
    qf1 = ld_frag(Qp + (size_t)qrow * DKH + 32 + lq * 8);
  }
  u32 nxt_raw = 0;
  if (t == 0) nxt_raw = atomicAdd(cnt, 1u);   // grab for NEXT item (published at diag)
  STAGE(Kp, Vp, 0, 0);
  STAGE(Kp, Vp, 1, 1);
  int base = 0;

  while (true) {
    f32x4 o4[4] = {};        // o4[dblk][r] = O[q=4lq+r][d=dblk*16+lr]
    f32x4 li4 = {};          // per-lane row-sum partials for q=lr

    // ---- off-diagonal k-tiles: no mask
    for (int kt = 0; kt < qt; ++kt) {
      const int cur = (base + kt) % 3;
      // retire S(kt) (oldest 4), keep S(kt+1) in flight; barrier publishes LDS writes
      asm volatile("s_waitcnt vmcnt(4)\n\ts_barrier" ::: "memory");
      if (kt + 2 <= qt) STAGE(Kp, Vp, kt + 2, (base + kt + 2) % 3);

      f32x4 st[4] = {};
      #pragma unroll
      for (int ksd = 0; ksd < 2; ++ksd)
        #pragma unroll
        for (int nt = 0; nt < 4; ++nt) {
          int sig = 32 * (nt >> 1) + 8 * (lr >> 2) + 4 * (nt & 1) + (lr & 3);
          int slot = (ksd * 4 + lq) ^ (lr & 7);
          bf16x8 kb = ld_frag(&lK[cur][sig * 64 + slot * 8]);
          st[nt] = __builtin_amdgcn_mfma_f32_16x16x32_bf16(kb, (ksd == 0) ? qf0 : qf1, st[nt], 0, 0, 0);
        }

      float p[4][4];
      #pragma unroll
      for (int nt = 0; nt < 4; ++nt)
        #pragma unroll
        for (int r = 0; r < 4; ++r) {
          p[nt][r] = fast_exp2(st[nt][r]);
          li4[r] += p[nt][r];
        }

      #pragma unroll
      for (int ks = 0; ks < 2; ++ks) {
        us8 av;
        #pragma unroll
        for (int j = 0; j < 4; ++j) {
          av[j] = f2bf(p[2 * ks][j]);
          av[4 + j] = f2bf(p[2 * ks + 1][j]);
        }
        bf16x8 pa = __builtin_bit_cast(bf16x8, av);
        #pragma unroll
        for (int dblk = 0; dblk < 4; ++dblk) {
          int d = dblk * 16 + lr;
          int sw = (d & 3) | (((d >> 3) & 1) << 2);
          int slot = (4 * ks + lq) ^ sw;
          bf16x8 vb = ld_frag(&lV[cur][d * 64 + slot * 8]);
          o4[dblk] = __builtin_amdgcn_mfma_f32_16x16x32_bf16(pa, vb, o4[dblk], 0, 0, 0);
        }
      }
    }

    // ---- diagonal k-tile (kt == qt): publish next grab, prefetch next item, masked compute
    const int dsel = (base + qt) % 3;
    if (t == 0) s_item[phase ^ 1] = (int)nxt_raw;   // LDS write ordered before barrier below
    asm volatile("s_waitcnt vmcnt(0)\n\ts_barrier" ::: "memory");
    const int nitem = s_item[phase ^ 1];
    const bool have_next = (nitem < 1024);

    int nqt = 0, nbh = 0, nbase = 0;
    const u16 *Kn = nullptr, *Vn = nullptr;
    bf16x8 qfN0 = {}, qfN1 = {};
    if (have_next) {
      nqt = 31 - (nitem >> 5);
      nbh = nitem & 31;
      const u16* Qn = Q + (size_t)nbh * S_LEN * DKH;
      Kn = K + (size_t)nbh * S_LEN * DKH;
      Vn = Vt + (size_t)nbh * DKH * S_LEN;
      int nqrow = nqt * 64 + w * 16 + lr;
      qfN0 = ld_frag(Qn + (size_t)nqrow * DKH + lq * 8);        // issued FIRST (oldest)
      qfN1 = ld_frag(Qn + (size_t)nqrow * DKH + 32 + lq * 8);
      nbase = (base + qt + 1) % 3;
      STAGE(Kn, Vn, 0, nbase);                                   // S0n (next-oldest)
      STAGE(Kn, Vn, 1, (nbase + 1) % 3);                         // S1n
      // WAR safe: buffers (base+qt+1)%3, (base+qt+2)%3 were last read at tiles qt-2/qt-1,
      // whose compute finished before the barrier above.
    }

    {
      f32x4 st[4] = {};
      #pragma unroll
      for (int ksd = 0; ksd < 2; ++ksd)
        #pragma unroll
        for (int nt = 0; nt < 4; ++nt) {
          int sig = 32 * (nt >> 1) + 8 * (lr >> 2) + 4 * (nt & 1) + (lr & 3);
          int slot = (ksd * 4 + lq) ^ (lr & 7);
          bf16x8 kb = ld_frag(&lK[dsel][sig * 64 + slot * 8]);
          st[nt] = __builtin_amdgcn_mfma_f32_16x16x32_bf16(kb, (ksd == 0) ? qf0 : qf1, st[nt], 0, 0, 0);
        }

      float p[4][4];
      const int qloc = w * 16 + lr;
      #pragma unroll
      for (int nt = 0; nt < 4; ++nt)
        #pragma unroll
        for (int r = 0; r < 4; ++r) {
          int kk = 32 * (nt >> 1) + 8 * lq + 4 * (nt & 1) + r;
          float e = fast_exp2(st[nt][r]);
          p[nt][r] = (kk > qloc) ? 0.0f : e;
          li4[r] += p[nt][r];
        }

      #pragma unroll
      for (int ks = 0; ks < 2; ++ks) {
        us8 av;
        #pragma unroll
        for (int j = 0; j < 4; ++j) {
          av[j] = f2bf(p[2 * ks][j]);
          av[4 + j] = f2bf(p[2 * ks + 1][j]);
        }
        bf16x8 pa = __builtin_bit_cast(bf16x8, av);
        #pragma unroll
        for (int dblk = 0; dblk < 4; ++dblk) {
          int d = dblk * 16 + lr;
          int sw = (d & 3) | (((d >> 3) & 1) << 2);
          int slot = (4 * ks + lq) ^ sw;
          bf16x8 vb = ld_frag(&lV[dsel][d * 64 + slot * 8]);
          o4[dblk] = __builtin_amdgcn_mfma_f32_16x16x32_bf16(pa, vb, o4[dblk], 0, 0, 0);
        }
      }
    }

    // li finalize: per-lane sum (q=lr), reduce over the 4 lq-replicas
    float li = li4[0] + li4[1] + li4[2] + li4[3];
    li += __shfl_xor(li, 16);
    li += __shfl_xor(li, 32);
    float ri[4];
    #pragma unroll
    for (int r = 0; r < 4; ++r) ri[r] = 1.0f / __shfl(li, lq * 4 + r);

    // epilogue: O[q][d], q = qt*64 + w*16 + 4lq+r, d = h*64 + dblk*16 + lr
    // (stores issued AFTER the prefetch loads -> vmcnt(4) at next kt=0 keeps S1n in flight)
    const size_t obase = ((size_t)b * S_LEN + qt * 64 + w * 16) * D_DIM + h * DKH;
    #pragma unroll
    for (int dblk = 0; dblk < 4; ++dblk)
      #pragma unroll
      for (int r = 0; r < 4; ++r)
        O[obase + (size_t)(lq * 4 + r) * D_DIM + dblk * 16 + lr] = f2bf(o4[dblk][r] * ri[r]);

    if (!have_next) break;
    // ---- rotate to next item
    qt = nqt; bh = nbh; b = bh >> 4; h = bh & 15;
    Kp = Kn; Vp = Vn; qf0 = qfN0; qf1 = qfN1;
    base = nbase; phase ^= 1;
    if (t == 0) nxt_raw = atomicAdd(cnt, 1u);   // grab for the item after next
  }
  #undef STAGE
}

extern "C" void kernel_launch(void* const* d_in, const int* in_sizes, int n_in,
                              void* d_out, int out_size, void* d_ws, size_t ws_size,
                              hipStream_t stream) {
  const float* query = (const float*)d_in[0];
  const float* key   = (const float*)d_in[1];
  const float* value = (const float*)d_in[2];
  // d_in[3] = causal mask (bool, triu k=1): structure known, not read
  const float* Wq = (const float*)d_in[4];
  const float* bq = (const float*)d_in[5];
  const float* Wk = (const float*)d_in[6];
  const float* bk = (const float*)d_in[7];
  const float* Wv = (const float*)d_in[8];
  const float* bv = (const float*)d_in[9];
  const float* Wo = (const float*)d_in[10];
  const float* bo = (const float*)d_in[11];
  float* out = (float*)d_out;

  const float qscale = 0.125f * 1.44269504088896341f;  // 1/sqrt(64) * log2(e)
  dim3 blk(256);

  u16* base = (u16*)d_ws;
  u16* Qb = base;                 // (B,H,S,DK) bf16, pre-scaled   [0, 4Mi)
  u16* Kb = base + 4 * Mi;        // (B,H,S,DK) bf16               [4Mi, 8Mi)
  u16* Vb = base + 8 * Mi;        // (B,H,DK,S) bf16               [8Mi, 12Mi)

  // convert-once region [12Mi, 28Mi) elems
  u16* cvt = base + 12 * Mi;
  u16* qbf = cvt;
  u16* kbf = cvt + 4 * Mi;
  u16* vbf = cvt + 8 * Mi;
  u16* wqb = cvt + 12 * Mi;
  u16* wkb = cvt + 13 * Mi;
  u16* wvb = cvt + 14 * Mi;
  u16* wob = cvt + 15 * Mi;
  u16* Ab  = qbf;                 // aliases qbf (dead after QKV GEMM)

  // attn work counter: d_out[0] (zeroed by cvt_all, consumed by attn,
  // overwritten by gemm_out_bb afterwards; all stream-ordered).
  u32* cnt = (u32*)d_out;

  cvt_all<<<dim3(8192), blk, 0, stream>>>(query, key, value, Wq, Wk, Wv, Wo, cvt, cnt);
  gemm_qkv_bb<<<dim3(8, 32, 3), blk, 0, stream>>>(qbf, kbf, vbf, wqb, wkb, wvb,
                                                  bq, bk, bv, Qb, Kb, Vb, qscale);
  attn_fused<<<dim3(768), blk, 0, stream>>>(Qb, Kb, Vb, Ab, cnt);
  gemm_out_bb<<<dim3(512), blk, 0, stream>>>(Ab, wob, bo, out);
}

// Round 11
// 230.797 us; speedup vs baseline: 1.0761x; 1.0666x over previous
//
#include <hip/hip_runtime.h>

// MultiHeadAttention: B=2, S=2048, D=1024, H=16, DK=64, causal. FP32 I/O.
// R20: fix R19's grab timing. R19 grabbed next-item at item START (+ 2 grabs at bootstrap)
// -> 768 blocks x 2 = 1536 >= 1024 items claimed instantly -> static assignment, adjacent
// items share qt -> makespan ~64 units (measured 62.8us). Now the grab is issued at
// kt == qt-1 (one tile before item end; qt==0: just before publication): atomic latency
// hides under the last off-diag tile, blocks hold <=1 future item for <=1 tile -> LPT
// restored. Pipeline kept from R19: diag-phase prefetch of qfN+S0n+S1n into free mod-3
// buffers, ping-pong s_item[2], uniform vmcnt(4) (boundary over-wait ~300cy accepted,
// never under-waits: S(cur) always older than newest 4). Diag barrier hardened to
// vmcnt(0) lgkmcnt(0) (publishes t0's s_item LDS write).
// qkv = R0 byte-exact; out-proj (R4 + XCD remap), cvt unchanged.

typedef unsigned short u16;
typedef unsigned int u32;
typedef __attribute__((ext_vector_type(8))) __bf16 bf16x8;
typedef __attribute__((ext_vector_type(8))) unsigned short us8;
typedef __attribute__((ext_vector_type(4))) float f32x4;

#define S_LEN 2048
#define D_DIM 1024
#define NH 16
#define DKH 64
#define Mi 1048576ULL

__device__ __forceinline__ u16 f2bf(float f) {
  return __builtin_bit_cast(u16, (__bf16)f);   // RNE; HW cvt on gfx950
}
__device__ __forceinline__ bf16x8 ld_frag(const u16* p) {
  us8 v = *(const us8*)p;
  return __builtin_bit_cast(bf16x8, v);
}
__device__ __forceinline__ float fast_exp2(float x) {
  float r;
  asm("v_exp_f32 %0, %1" : "=v"(r) : "v"(x));   // scores pre-scaled: no denorm/range fixup needed
  return r;
}
// async global->LDS, 16B per lane; lds base must be wave-uniform (HW: base + lane*16)
__device__ __forceinline__ void gl2lds16(const u16* g, u16* l) {
  __builtin_amdgcn_global_load_lds(
      (__attribute__((address_space(1))) void*)(g),
      (__attribute__((address_space(3))) void*)(l), 16, 0, 0);
}

// ---- Prepass: convert q,k,v (4Mi elems each) + Wq,Wk,Wv,Wo (1Mi each) to bf16.
// Also zeroes the attn work-queue counter (d_out[0]; out-proj overwrites d_out later).
__global__ __launch_bounds__(256, 1) void cvt_all(
    const float* __restrict__ q, const float* __restrict__ k, const float* __restrict__ v,
    const float* __restrict__ wq, const float* __restrict__ wk,
    const float* __restrict__ wv, const float* __restrict__ wo,
    u16* __restrict__ dst, u32* __restrict__ cnt)
{
  if (blockIdx.x == 0 && threadIdx.x == 0) *cnt = 0;
  size_t e0 = ((size_t)blockIdx.x * 256 + threadIdx.x) * 8;
  const float* s;
  if      (e0 <  4*Mi) s = q  + e0;
  else if (e0 <  8*Mi) s = k  + (e0 - 4*Mi);
  else if (e0 < 12*Mi) s = v  + (e0 - 8*Mi);
  else if (e0 < 13*Mi) s = wq + (e0 - 12*Mi);
  else if (e0 < 14*Mi) s = wk + (e0 - 13*Mi);
  else if (e0 < 15*Mi) s = wv + (e0 - 14*Mi);
  else                 s = wo + (e0 - 15*Mi);
  float4 a = ((const float4*)s)[0];
  float4 b = ((const float4*)s)[1];
  us8 o;
  o[0]=f2bf(a.x); o[1]=f2bf(a.y); o[2]=f2bf(a.z); o[3]=f2bf(a.w);
  o[4]=f2bf(b.x); o[5]=f2bf(b.y); o[6]=f2bf(b.z); o[7]=f2bf(b.w);
  *(us8*)(dst + e0) = o;
}

// ---- QKV projection, pure bf16 (R0 version, byte-exact). z=0 (Q): (B,H,S,DK) scaled;
// z=1 (K): (B,H,S,DK); z=2 (V): (B,H,DK,S).
__global__ __launch_bounds__(256, 1) void gemm_qkv_bb(
    const u16* __restrict__ Aq, const u16* __restrict__ Ak, const u16* __restrict__ Av,
    const u16* __restrict__ Wqb, const u16* __restrict__ Wkb, const u16* __restrict__ Wvb,
    const float* __restrict__ bq, const float* __restrict__ bk, const float* __restrict__ bv,
    u16* __restrict__ Oq, u16* __restrict__ Ok, u16* __restrict__ Ov, float qscale)
{
  const int z = blockIdx.z;
  const u16* A = (z == 0) ? Aq : (z == 1) ? Ak : Av;
  const u16* W = (z == 0) ? Wqb : (z == 1) ? Wkb : Wvb;
  const float* bias = (z == 0) ? bq : (z == 1) ? bk : bv;
  u16* out = (z == 0) ? Oq : (z == 1) ? Ok : Ov;
  const float scale = (z == 0) ? qscale : 1.0f;
  const int K = 1024;

  __shared__ u16 lA[128 * 32];
  __shared__ u16 lB[128 * 32];
  const int t = threadIdx.x;
  const int w = t >> 6, l = t & 63;
  const int mblk = blockIdx.y * 128, nblk = blockIdx.x * 128;
  const int wm = (w & 1) * 64, wn = (w >> 1) * 64;
  const int lr = l & 15, lq = l >> 4;
  const int srow = l >> 2, scol = (l & 3) * 8;

  f32x4 acc[4][4] = {};

  for (int k0 = 0; k0 < K; k0 += 32) {
    __syncthreads();
    #pragma unroll
    for (int r = 0; r < 2; ++r) {
      int grp = r * 4 + w;
      gl2lds16(A + (size_t)(mblk + grp * 16 + srow) * K + k0 + scol, &lA[grp * 512]);
      gl2lds16(W + (size_t)(nblk + grp * 16 + srow) * K + k0 + scol, &lB[grp * 512]);
    }
    __syncthreads();
    bf16x8 aF[4], bF[4];
    #pragma unroll
    for (int mt = 0; mt < 4; ++mt)
      aF[mt] = ld_frag(&lA[(wm + mt * 16 + lr) * 32 + lq * 8]);
    #pragma unroll
    for (int nt = 0; nt < 4; ++nt)
      bF[nt] = ld_frag(&lB[(wn + nt * 16 + lr) * 32 + lq * 8]);
    #pragma unroll
    for (int mt = 0; mt < 4; ++mt)
      #pragma unroll
      for (int nt = 0; nt < 4; ++nt)
        acc[mt][nt] = __builtin_amdgcn_mfma_f32_16x16x32_bf16(aF[mt], bF[nt], acc[mt][nt], 0, 0, 0);
  }

  #pragma unroll
  for (int mt = 0; mt < 4; ++mt)
    #pragma unroll
    for (int nt = 0; nt < 4; ++nt)
      #pragma unroll
      for (int r = 0; r < 4; ++r) {
        int rowg = mblk + wm + mt * 16 + lq * 4 + r;   // C/D: row=(lane>>4)*4+reg
        int colg = nblk + wn + nt * 16 + lr;           //      col=lane&15
        float v = (acc[mt][nt][r] + bias[colg]) * scale;
        int b = rowg >> 11, s = rowg & 2047;
        int h = colg >> 6, dk = colg & 63;
        if (z != 2)
          out[(((size_t)(b * NH + h)) * S_LEN + s) * DKH + dk] = f2bf(v);
        else
          out[(((size_t)(b * NH + h)) * DKH + dk) * S_LEN + s] = f2bf(v);
      }
}

// ---- Out-proj, bf16 -> fp32. 128x64 tile, BK=64, single-buffer 2-sync (R4 version),
// flattened 512-grid with XCD-contiguous remap.
__global__ __launch_bounds__(256, 1) void gemm_out_bb(
    const u16* __restrict__ A, const u16* __restrict__ W,
    const float* __restrict__ bias, float* __restrict__ out)
{
  const int K = 1024;
  __shared__ u16 lA[128 * 64];   // 16 KiB
  __shared__ u16 lB[64 * 64];    //  8 KiB
  const int bid = blockIdx.x;
  const int o   = (bid & 7) * 64 + (bid >> 3);   // bijective: 512 = 8 XCD * 64
  const int mblk = (o >> 4) * 128, nblk = (o & 15) * 64;
  const int t = threadIdx.x;
  const int w = t >> 6, l = t & 63;
  const int wm = (w & 1) * 64, wn = (w >> 1) * 32;
  const int lr = l & 15, lq = l >> 4;
  const int srow = l >> 3;
  const int sgr  = (l & 7) ^ srow;

  f32x4 acc[4][2] = {};

  for (int k0 = 0; k0 < K; k0 += 64) {
    __syncthreads();
    #pragma unroll
    for (int i = 0; i < 4; ++i) {
      int chunk = w * 4 + i;
      int row = chunk * 8 + srow;
      gl2lds16(A + (size_t)(mblk + row) * K + k0 + sgr * 8, &lA[chunk * 512]);
    }
    #pragma unroll
    for (int i = 0; i < 2; ++i) {
      int chunk = w * 2 + i;               // 8 chunks of 8 rows for B
      int row = chunk * 8 + srow;
      gl2lds16(W + (size_t)(nblk + row) * K + k0 + sgr * 8, &lB[chunk * 512]);
    }
    __syncthreads();
    #pragma unroll
    for (int kk = 0; kk < 2; ++kk) {
      bf16x8 aF[4], bF[2];
      #pragma unroll
      for (int mt = 0; mt < 4; ++mt)
        aF[mt] = ld_frag(&lA[(wm + mt * 16 + lr) * 64 + ((kk * 4 + lq) ^ (lr & 7)) * 8]);
      #pragma unroll
      for (int nt = 0; nt < 2; ++nt)
        bF[nt] = ld_frag(&lB[(wn + nt * 16 + lr) * 64 + ((kk * 4 + lq) ^ (lr & 7)) * 8]);
      #pragma unroll
      for (int mt = 0; mt < 4; ++mt)
        #pragma unroll
        for (int nt = 0; nt < 2; ++nt)
          acc[mt][nt] = __builtin_amdgcn_mfma_f32_16x16x32_bf16(aF[mt], bF[nt], acc[mt][nt], 0, 0, 0);
    }
  }

  #pragma unroll
  for (int mt = 0; mt < 4; ++mt)
    #pragma unroll
    for (int nt = 0; nt < 2; ++nt)
      #pragma unroll
      for (int r = 0; r < 4; ++r) {
        int rowg = mblk + wm + mt * 16 + lq * 4 + r;
        int colg = nblk + wn + nt * 16 + lr;
        out[(size_t)rowg * D_DIM + colg] = acc[mt][nt][r] + bias[colg];
      }
}

// ---- MFMA flash attention (S^T, no-max softmax, register-resident P), causal.
// R20: 3-buffer counted vmcnt + LPT + diag peel + raw exp2 + cross-item pipelining with
// LATE grab (kt==qt-1). vmcnt order at item boundary: [qfN(2), S0n(4), S1n(4), stores(16)];
// next kt=0's vmcnt(4) retires through S1n+12 stores (over-wait ~300cy, never under-waits).
// S^T MFMA nt consumes K rows sigma(nt,m)=32(nt>>1)+8(m>>2)+4(nt&1)+(m&3): its C regs
// give lane lq the k-indices 8lq+j (j=4(nt&1)+r) == the PV A-operand packing. Zero P movement.
// LDS swizzle swz(row)=(row&3)|(((row>>3)&1)<<2): K-reads hit slot=(4ks+lq)^(lr&7) (verified even).
__global__ __launch_bounds__(256, 1) void attn_fused(
    const u16* __restrict__ Q, const u16* __restrict__ K,
    const u16* __restrict__ Vt, u16* __restrict__ O, u32* __restrict__ cnt)
{
  __shared__ u16 lK[3][64 * 64];   // 24 KiB
  __shared__ u16 lV[3][64 * 64];   // 24 KiB
  __shared__ int s_item[2];

  const int t = threadIdx.x;
  const int w = t >> 6, l = t & 63;
  const int lr = l & 15, lq = l >> 4;
  const int srow8 = l >> 3;            // staging: row within 8-row group
  const int schunk = l & 7;            // staging: LDS slot chunk this lane fills

  #define STAGE(KP, VP, T, bsel)                                                   \
    do {                                                                           \
      _Pragma("unroll")                                                            \
      for (int r2 = 0; r2 < 2; ++r2) {                                             \
        int grp = r2 * 4 + w;                                                      \
        int row = grp * 8 + srow8;                                                 \
        int sw = (row & 3) | (((row >> 3) & 1) << 2);                              \
        int c = schunk ^ sw;                                                       \
        gl2lds16((KP) + (size_t)((T) * 64 + row) * DKH + c * 8, &lK[bsel][grp * 512]); \
        gl2lds16((VP) + (size_t)row * S_LEN + (T) * 64 + c * 8, &lV[bsel][grp * 512]); \
      }                                                                            \
    } while (0)

  // ---- bootstrap: first item only (next is grabbed at kt==qt-1)
  if (t == 0) s_item[0] = (int)atomicAdd(cnt, 1u);
  __syncthreads();
  int item = s_item[0];
  if (item >= 1024) return;
  int phase = 0;
  int qt = 31 - (item >> 5);           // heaviest first (LPT)
  int bh = item & 31;
  int b = bh >> 4, h = bh & 15;

  const u16* Kp = K + (size_t)bh * S_LEN * DKH;
  const u16* Vp = Vt + (size_t)bh * DKH * S_LEN;
  bf16x8 qf0, qf1;
  {
    const u16* Qp = Q + (size_t)bh * S_LEN * DKH;
    int qrow = qt * 64 + w * 16 + lr;
    qf0 = ld_frag(Qp + (size_t)qrow * DKH + lq * 8);
    qf1 = ld_frag(Qp + (size_t)qrow * DKH + 32 + lq * 8);
  }
  u32 nxt_raw = 0;
  STAGE(Kp, Vp, 0, 0);
  STAGE(Kp, Vp, 1, 1);
  int base = 0;

  while (true) {
    f32x4 o4[4] = {};        // o4[dblk][r] = O[q=4lq+r][d=dblk*16+lr]
    f32x4 li4 = {};          // per-lane row-sum partials for q=lr

    // ---- off-diagonal k-tiles: no mask
    for (int kt = 0; kt < qt; ++kt) {
      const int cur = (base + kt) % 3;
      // retire S(kt) (oldest outstanding), keep S(kt+1) in flight; barrier publishes LDS
      asm volatile("s_waitcnt vmcnt(4)\n\ts_barrier" ::: "memory");
      if (kt + 2 <= qt) STAGE(Kp, Vp, kt + 2, (base + kt + 2) % 3);
      // late grab: one tile before item end -> atomic latency hides under this tile
      if (t == 0 && kt == qt - 1) nxt_raw = atomicAdd(cnt, 1u);

      f32x4 st[4] = {};
      #pragma unroll
      for (int ksd = 0; ksd < 2; ++ksd)
        #pragma unroll
        for (int nt = 0; nt < 4; ++nt) {
          int sig = 32 * (nt >> 1) + 8 * (lr >> 2) + 4 * (nt & 1) + (lr & 3);
          int slot = (ksd * 4 + lq) ^ (lr & 7);
          bf16x8 kb = ld_frag(&lK[cur][sig * 64 + slot * 8]);
          st[nt] = __builtin_amdgcn_mfma_f32_16x16x32_bf16(kb, (ksd == 0) ? qf0 : qf1, st[nt], 0, 0, 0);
        }

      float p[4][4];
      #pragma unroll
      for (int nt = 0; nt < 4; ++nt)
        #pragma unroll
        for (int r = 0; r < 4; ++r) {
          p[nt][r] = fast_exp2(st[nt][r]);
          li4[r] += p[nt][r];
        }

      #pragma unroll
      for (int ks = 0; ks < 2; ++ks) {
        us8 av;
        #pragma unroll
        for (int j = 0; j < 4; ++j) {
          av[j] = f2bf(p[2 * ks][j]);
          av[4 + j] = f2bf(p[2 * ks + 1][j]);
        }
        bf16x8 pa = __builtin_bit_cast(bf16x8, av);
        #pragma unroll
        for (int dblk = 0; dblk < 4; ++dblk) {
          int d = dblk * 16 + lr;
          int sw = (d & 3) | (((d >> 3) & 1) << 2);
          int slot = (4 * ks + lq) ^ sw;
          bf16x8 vb = ld_frag(&lV[cur][d * 64 + slot * 8]);
          o4[dblk] = __builtin_amdgcn_mfma_f32_16x16x32_bf16(pa, vb, o4[dblk], 0, 0, 0);
        }
      }
    }

    // ---- diagonal k-tile (kt == qt): publish grab, prefetch next item, masked compute
    if (t == 0 && qt == 0) nxt_raw = atomicAdd(cnt, 1u);   // light items: no off-diag tile
    const int dsel = (base + qt) % 3;
    if (t == 0) s_item[phase ^ 1] = (int)nxt_raw;
    asm volatile("s_waitcnt vmcnt(0) lgkmcnt(0)\n\ts_barrier" ::: "memory");
    const int nitem = s_item[phase ^ 1];
    const bool have_next = (nitem < 1024);

    int nqt = 0, nbh = 0, nbase = 0;
    const u16 *Kn = nullptr, *Vn = nullptr;
    bf16x8 qfN0 = {}, qfN1 = {};
    if (have_next) {
      nqt = 31 - (nitem >> 5);
      nbh = nitem & 31;
      const u16* Qn = Q + (size_t)nbh * S_LEN * DKH;
      Kn = K + (size_t)nbh * S_LEN * DKH;
      Vn = Vt + (size_t)nbh * DKH * S_LEN;
      int nqrow = nqt * 64 + w * 16 + lr;
      qfN0 = ld_frag(Qn + (size_t)nqrow * DKH + lq * 8);        // issued FIRST (oldest)
      qfN1 = ld_frag(Qn + (size_t)nqrow * DKH + 32 + lq * 8);
      nbase = (base + qt + 1) % 3;
      STAGE(Kn, Vn, 0, nbase);                                   // S0n
      STAGE(Kn, Vn, 1, (nbase + 1) % 3);                         // S1n
      // WAR safe: buffers (base+qt+1)%3, (base+qt+2)%3 last read at tiles qt-2/qt-1,
      // whose compute finished before the barrier above.
    }

    {
      f32x4 st[4] = {};
      #pragma unroll
      for (int ksd = 0; ksd < 2; ++ksd)
        #pragma unroll
        for (int nt = 0; nt < 4; ++nt) {
          int sig = 32 * (nt >> 1) + 8 * (lr >> 2) + 4 * (nt & 1) + (lr & 3);
          int slot = (ksd * 4 + lq) ^ (lr & 7);
          bf16x8 kb = ld_frag(&lK[dsel][sig * 64 + slot * 8]);
          st[nt] = __builtin_amdgcn_mfma_f32_16x16x32_bf16(kb, (ksd == 0) ? qf0 : qf1, st[nt], 0, 0, 0);
        }

      float p[4][4];
      const int qloc = w * 16 + lr;
      #pragma unroll
      for (int nt = 0; nt < 4; ++nt)
        #pragma unroll
        for (int r = 0; r < 4; ++r) {
          int kk = 32 * (nt >> 1) + 8 * lq + 4 * (nt & 1) + r;
          float e = fast_exp2(st[nt][r]);
          p[nt][r] = (kk > qloc) ? 0.0f : e;
          li4[r] += p[nt][r];
        }

      #pragma unroll
      for (int ks = 0; ks < 2; ++ks) {
        us8 av;
        #pragma unroll
        for (int j = 0; j < 4; ++j) {
          av[j] = f2bf(p[2 * ks][j]);
          av[4 + j] = f2bf(p[2 * ks + 1][j]);
        }
        bf16x8 pa = __builtin_bit_cast(bf16x8, av);
        #pragma unroll
        for (int dblk = 0; dblk < 4; ++dblk) {
          int d = dblk * 16 + lr;
          int sw = (d & 3) | (((d >> 3) & 1) << 2);
          int slot = (4 * ks + lq) ^ sw;
          bf16x8 vb = ld_frag(&lV[dsel][d * 64 + slot * 8]);
          o4[dblk] = __builtin_amdgcn_mfma_f32_16x16x32_bf16(pa, vb, o4[dblk], 0, 0, 0);
        }
      }
    }

    // li finalize: per-lane sum (q=lr), reduce over the 4 lq-replicas
    float li = li4[0] + li4[1] + li4[2] + li4[3];
    li += __shfl_xor(li, 16);
    li += __shfl_xor(li, 32);
    float ri[4];
    #pragma unroll
    for (int r = 0; r < 4; ++r) ri[r] = 1.0f / __shfl(li, lq * 4 + r);

    // epilogue: O[q][d], q = qt*64 + w*16 + 4lq+r, d = h*64 + dblk*16 + lr
    // (stores issued AFTER the prefetch loads -> boundary vmcnt(4) never under-waits)
    const size_t obase = ((size_t)b * S_LEN + qt * 64 + w * 16) * D_DIM + h * DKH;
    #pragma unroll
    for (int dblk = 0; dblk < 4; ++dblk)
      #pragma unroll
      for (int r = 0; r < 4; ++r)
        O[obase + (size_t)(lq * 4 + r) * D_DIM + dblk * 16 + lr] = f2bf(o4[dblk][r] * ri[r]);

    if (!have_next) break;
    // ---- rotate to next item
    qt = nqt; bh = nbh; b = bh >> 4; h = bh & 15;
    Kp = Kn; Vp = Vn; qf0 = qfN0; qf1 = qfN1;
    base = nbase; phase ^= 1;
  }
  #undef STAGE
}

extern "C" void kernel_launch(void* const* d_in, const int* in_sizes, int n_in,
                              void* d_out, int out_size, void* d_ws, size_t ws_size,
                              hipStream_t stream) {
  const float* query = (const float*)d_in[0];
  const float* key   = (const float*)d_in[1];
  const float* value = (const float*)d_in[2];
  // d_in[3] = causal mask (bool, triu k=1): structure known, not read
  const float* Wq = (const float*)d_in[4];
  const float* bq = (const float*)d_in[5];
  const float* Wk = (const float*)d_in[6];
  const float* bk = (const float*)d_in[7];
  const float* Wv = (const float*)d_in[8];
  const float* bv = (const float*)d_in[9];
  const float* Wo = (const float*)d_in[10];
  const float* bo = (const float*)d_in[11];
  float* out = (float*)d_out;

  const float qscale = 0.125f * 1.44269504088896341f;  // 1/sqrt(64) * log2(e)
  dim3 blk(256);

  u16* base = (u16*)d_ws;
  u16* Qb = base;                 // (B,H,S,DK) bf16, pre-scaled   [0, 4Mi)
  u16* Kb = base + 4 * Mi;        // (B,H,S,DK) bf16               [4Mi, 8Mi)
  u16* Vb = base + 8 * Mi;        // (B,H,DK,S) bf16               [8Mi, 12Mi)

  // convert-once region [12Mi, 28Mi) elems
  u16* cvt = base + 12 * Mi;
  u16* qbf = cvt;
  u16* kbf = cvt + 4 * Mi;
  u16* vbf = cvt + 8 * Mi;
  u16* wqb = cvt + 12 * Mi;
  u16* wkb = cvt + 13 * Mi;
  u16* wvb = cvt + 14 * Mi;
  u16* wob = cvt + 15 * Mi;
  u16* Ab  = qbf;                 // aliases qbf (dead after QKV GEMM)

  // attn work counter: d_out[0] (zeroed by cvt_all, consumed by attn,
  // overwritten by gemm_out_bb afterwards; all stream-ordered).
  u32* cnt = (u32*)d_out;

  cvt_all<<<dim3(8192), blk, 0, stream>>>(query, key, value, Wq, Wk, Wv, Wo, cvt, cnt);
  gemm_qkv_bb<<<dim3(8, 32, 3), blk, 0, stream>>>(qbf, kbf, vbf, wqb, wkb, wvb,
                                                  bq, bk, bv, Qb, Kb, Vb, qscale);
  attn_fused<<<dim3(768), blk, 0, stream>>>(Qb, Kb, Vb, Ab, cnt);
  gemm_out_bb<<<dim3(512), blk, 0, stream>>>(Ab, wob, bo, out);
}